// Round 13
// baseline (529.989 us; speedup 1.0000x reference)
//
#include <hip/hip_runtime.h>
#include <hip/hip_bf16.h>

#define Vn   196608
#define NNZn 1769472
#define Bn   4
#define Pn   64
#define Qn   64
#define VPn  (Vn*Pn)
#define NB   256      // buckets
#define RPB  768      // rows per bucket = Vn/NB
#define EPT  4096     // edges per count/bucket tile
#define NTIL 432      // NNZ/EPT

typedef __hip_bfloat16 bf16;
typedef __attribute__((ext_vector_type(8))) short bf16x8;
typedef __attribute__((ext_vector_type(4))) float f32x4;
typedef __attribute__((ext_vector_type(4))) unsigned int u32x4;

__device__ inline short f2bs(float f){
  __hip_bfloat16 h = __float2bfloat16(f);
  return *(short*)&h;
}
__device__ inline float lo16(unsigned u){ return __uint_as_float(u<<16); }
__device__ inline float hi16(unsigned u){ return __uint_as_float(u & 0xffff0000u); }

// ---- fused pre-pass: bucket-count (LDS-aggregated) + cvt + prepw ----------

__global__ __launch_bounds__(256) void k_pre(const int* __restrict__ rows, unsigned* __restrict__ gcount,
                      const float* __restrict__ x, short* __restrict__ x0c,
                      const float* __restrict__ wf, short* __restrict__ wcb){
  __shared__ unsigned hcnt[NB];
  const int bid = blockIdx.x, t = threadIdx.x;
  if(bid % 58 == 0){               // ---- count: LDS hist over 256 buckets
    const int cb = bid/58;
    hcnt[t] = 0u;
    __syncthreads();
    const int base = cb*EPT;
#pragma unroll
    for(int k=0;k<4;++k){
      const int4 r = *(const int4*)(rows + base + k*1024 + t*4);
      atomicAdd(&hcnt[(unsigned)r.x/RPB], 1u);
      atomicAdd(&hcnt[(unsigned)r.y/RPB], 1u);
      atomicAdd(&hcnt[(unsigned)r.z/RPB], 1u);
      atomicAdd(&hcnt[(unsigned)r.w/RPB], 1u);
    }
    __syncthreads();
    atomicAdd(&gcount[t], hcnt[t]);
    return;
  }
  const int f = bid - bid/58 - 1;
  if(f < 24576){                   // ---- cvt: 8 floats -> 8 bf16 per thread
    const int i = f*256 + t;
    const int o = i*8;
    const int v = o>>8, bp = o&255;
    const int hh = bp>>7, w7 = bp&127;
    const int b = (hh<<1) + (w7>>6), p = w7&63;
    const float* xp = x + (size_t)b*VPn + (size_t)v*64 + p;
    const float4 f0 = *(const float4*)xp;
    const float4 f1 = *(const float4*)(xp+4);
    unsigned r0 = ((unsigned)(unsigned short)f2bs(f0.y)<<16) | (unsigned)(unsigned short)f2bs(f0.x);
    unsigned r1 = ((unsigned)(unsigned short)f2bs(f0.w)<<16) | (unsigned)(unsigned short)f2bs(f0.z);
    unsigned r2 = ((unsigned)(unsigned short)f2bs(f1.y)<<16) | (unsigned)(unsigned short)f2bs(f1.x);
    unsigned r3 = ((unsigned)(unsigned short)f2bs(f1.w)<<16) | (unsigned)(unsigned short)f2bs(f1.z);
    u32x4 u; u[0]=r0; u[1]=r1; u[2]=r2; u[3]=r3;
    *(u32x4*)(x0c + ((size_t)hh*Vn + v)*128 + w7) = u;
  } else {                         // ---- prepw: combined weights wcb[q][192]
    const int idx = (f - 24576)*256 + t;         // 12288 total
    const int q = idx/192, rem = idx%192, part = rem>>6, p = rem&63;
    float w;
    if(part==0)      w = wf[(3*p+0)*64+q] - wf[(3*p+2)*64+q];
    else if(part==1) w = wf[(3*p+1)*64+q];
    else             w = 2.0f*wf[(3*p+2)*64+q];
    wcb[idx] = f2bs(w);
  }
}

// ---- scan of 256 bucket counts -> exclusive bases + cursors ----
__global__ void k_scan256(const unsigned* __restrict__ gcount, unsigned* __restrict__ gbase,
                          unsigned* __restrict__ gcursor){
  __shared__ unsigned t[NB];
  const int i = threadIdx.x;
  const unsigned c = gcount[i];
  t[i] = c;
  __syncthreads();
  for(int off=1; off<NB; off<<=1){
    unsigned v = (i>=off) ? t[i-off] : 0u;
    __syncthreads();
    t[i] += v;
    __syncthreads();
  }
  const unsigned excl = t[i] - c;
  gbase[i] = excl;
  gcursor[i] = excl;
  if(i == NB-1) gbase[NB] = t[NB-1];
}

// ---- bucket scatter: edges -> bucket-grouped (brow, bmeta) ----
__global__ __launch_bounds__(256) void k_bucket(const int* __restrict__ rows, const int* __restrict__ cols,
                         const float* __restrict__ vals, unsigned* __restrict__ gcursor,
                         int* __restrict__ brow, int2* __restrict__ bmeta){
  __shared__ unsigned hcnt[NB];
  __shared__ unsigned lcur[NB];
  const int t = threadIdx.x;
  const int base = blockIdx.x*EPT;
  hcnt[t] = 0u;
  __syncthreads();
  int4 r4[4];
#pragma unroll
  for(int k=0;k<4;++k){
    r4[k] = *(const int4*)(rows + base + k*1024 + t*4);
    atomicAdd(&hcnt[(unsigned)r4[k].x/RPB], 1u);
    atomicAdd(&hcnt[(unsigned)r4[k].y/RPB], 1u);
    atomicAdd(&hcnt[(unsigned)r4[k].z/RPB], 1u);
    atomicAdd(&hcnt[(unsigned)r4[k].w/RPB], 1u);
  }
  __syncthreads();
  lcur[t] = atomicAdd(&gcursor[t], hcnt[t]);
  __syncthreads();
#pragma unroll
  for(int k=0;k<4;++k){
    const int4   c4 = *(const int4*)(cols + base + k*1024 + t*4);
    const float4 v4 = *(const float4*)(vals + base + k*1024 + t*4);
    unsigned p;
    p = atomicAdd(&lcur[(unsigned)r4[k].x/RPB],1u); brow[p]=r4[k].x; { int2 m; m.x=c4.x; m.y=__float_as_int(v4.x); bmeta[p]=m; }
    p = atomicAdd(&lcur[(unsigned)r4[k].y/RPB],1u); brow[p]=r4[k].y; { int2 m; m.x=c4.y; m.y=__float_as_int(v4.y); bmeta[p]=m; }
    p = atomicAdd(&lcur[(unsigned)r4[k].z/RPB],1u); brow[p]=r4[k].z; { int2 m; m.x=c4.z; m.y=__float_as_int(v4.z); bmeta[p]=m; }
    p = atomicAdd(&lcur[(unsigned)r4[k].w/RPB],1u); brow[p]=r4[k].w; { int2 m; m.x=c4.w; m.y=__float_as_int(v4.w); bmeta[p]=m; }
  }
}

// ---- per-bucket CSR finalize: one block per bucket, all in LDS ----
__global__ __launch_bounds__(256) void k_csr(const int* __restrict__ brow, const int2* __restrict__ bmeta,
                      const unsigned* __restrict__ gbase,
                      unsigned* __restrict__ rstart, unsigned* __restrict__ rend,
                      int2* __restrict__ meta){
  __shared__ unsigned rcnt[RPB];
  __shared__ unsigned rcur[RPB];
  __shared__ unsigned ssum[256];
  const int t = threadIdx.x, b = blockIdx.x;
  const unsigned base = gbase[b];
  const int nb = (int)(gbase[b+1] - base);
  const int rv0 = b*RPB;
#pragma unroll
  for(int k=0;k<3;++k) rcnt[t*3+k] = 0u;
  __syncthreads();
  for(int e=t; e<nb; e+=256){
    const int r = brow[base+e] - rv0;
    atomicAdd(&rcnt[r], 1u);
  }
  __syncthreads();
  const unsigned c0 = rcnt[t*3], c1 = rcnt[t*3+1], c2 = rcnt[t*3+2];
  const unsigned mysum = c0+c1+c2;
  ssum[t] = mysum;
  __syncthreads();
  for(int off=1; off<256; off<<=1){
    unsigned v = (t>=off) ? ssum[t-off] : 0u;
    __syncthreads();
    ssum[t] += v;
    __syncthreads();
  }
  const unsigned excl = ssum[t] - mysum;
  const unsigned s0 = base + excl, s1 = s0 + c0, s2 = s1 + c1;
  rstart[rv0+t*3+0] = s0;  rend[rv0+t*3+0] = s0 + c0;  rcur[t*3+0] = s0;
  rstart[rv0+t*3+1] = s1;  rend[rv0+t*3+1] = s1 + c1;  rcur[t*3+1] = s1;
  rstart[rv0+t*3+2] = s2;  rend[rv0+t*3+2] = s2 + c2;  rcur[t*3+2] = s2;
  __syncthreads();
  for(int e=t; e<nb; e+=256){
    const int r = brow[base+e] - rv0;
    const unsigned pos = atomicAdd(&rcur[r], 1u);
    meta[pos] = bmeta[base+e];
  }
}

// ---------------- SpMM: TWO rows per wave (R5-proven shape) ---------------

#define SP_STAGE(U,W,I) { int c_=0; float wv_=0.f; \
    if((I) < n){ const int2 m_ = meta[s+(unsigned)(I)]; c_=m_.x; wv_=__int_as_float(m_.y);} \
    W = wv_; U = *(const u32x4*)(src + (size_t)c_*SROW + off); }
#define SP_CONSUME(U,W) { \
    a0=fmaf(W,lo16(U[0]),a0); a1=fmaf(W,hi16(U[0]),a1); \
    a2=fmaf(W,lo16(U[1]),a2); a3=fmaf(W,hi16(U[1]),a3); \
    a4=fmaf(W,lo16(U[2]),a4); a5=fmaf(W,hi16(U[2]),a5); \
    a6=fmaf(W,lo16(U[3]),a6); a7=fmaf(W,hi16(U[3]),a7); }
#define SP_BODY \
  float a0=0,a1=0,a2=0,a3=0,a4=0,a5=0,a6=0,a7=0; \
  if(nmax > 0){ \
    u32x4 u0,u1,u2,u3; float w0,w1,w2,w3; \
    SP_STAGE(u0,w0,0) SP_STAGE(u1,w1,1) SP_STAGE(u2,w2,2) SP_STAGE(u3,w3,3) \
    int rem = nmax - 4; \
    int j = 4; \
    while(rem > 0){ \
      const u32x4 p0=u0, p1=u1, p2=u2, p3=u3; \
      const float q0=w0, q1=w1, q2=w2, q3=w3; \
      SP_STAGE(u0,w0,j) SP_STAGE(u1,w1,j+1) SP_STAGE(u2,w2,j+2) SP_STAGE(u3,w3,j+3) \
      SP_CONSUME(p0,q0) SP_CONSUME(p1,q1) SP_CONSUME(p2,q2) SP_CONSUME(p3,q3) \
      rem -= 4; j += 4; \
    } \
    SP_CONSUME(u0,w0) SP_CONSUME(u1,w1) SP_CONSUME(u2,w2) SP_CONSUME(u3,w3) \
  } \
  unsigned r0 = ((unsigned)(unsigned short)f2bs(a1)<<16) | (unsigned)(unsigned short)f2bs(a0); \
  unsigned r1 = ((unsigned)(unsigned short)f2bs(a3)<<16) | (unsigned)(unsigned short)f2bs(a2); \
  unsigned r2 = ((unsigned)(unsigned short)f2bs(a5)<<16) | (unsigned)(unsigned short)f2bs(a4); \
  unsigned r3 = ((unsigned)(unsigned short)f2bs(a7)<<16) | (unsigned)(unsigned short)f2bs(a6); \
  u32x4 ov; ov[0]=r0; ov[1]=r1; ov[2]=r2; ov[3]=r3;

template<int SROW, size_t PSTR>
__global__ __launch_bounds__(256) void k_spmm(const short* __restrict__ src,
                          const int2* __restrict__ meta,
                          const unsigned* __restrict__ rstart, const unsigned* __restrict__ rend,
                          short* __restrict__ dst){
  const int tid = threadIdx.x;
  const int lane = tid & 63;
  const int half = lane >> 5, sub = lane & 31;
  const int vbase = blockIdx.x*8 + (tid>>6)*2;
  const unsigned sA = rstart[vbase],   sB = rstart[vbase+1];
  const int nA = (int)(rend[vbase]-sA), nB = (int)(rend[vbase+1]-sB);
  const int nmax = (nA > nB) ? nA : nB;
  const unsigned s = half ? sB : sA;
  const int n = half ? nB : nA;
  const size_t off = (size_t)(sub>>4)*PSTR + (size_t)((sub&15)*8);
  SP_BODY
  *(u32x4*)(dst + (size_t)(vbase+half)*256 + sub*8) = ov;
}

// ---------------- MFMA GEMM epilogue — no LDS, direct wcb B-frags ----------
// out[b,v,q] = bias[q] + sum_k3 A[v-row,k3] * Wc[k3,q]
// B-frags read straight from wcb (24 KB, L1-resident, wave-uniform per
// 16-lane group -> broadcast). LDS=0 lifts occupancy for this streaming
// kernel (was LDS-capped at ~23%). 2-deep A-load pipeline retained.
// mfma_f32_16x16x32_bf16: A row=l&15, k=8*(l>>4)+i; C/D col=l&15, row=4*(l>>4)+reg.

#define LOADA(dst, cc) { \
  const int part_ = (cc)>>1, ko_ = ((cc)&1)*32; \
  if(part_==0){ \
    const short* sp = x0 + ((size_t)(w>>1)*Vn + v0 + r)*128 + (w&1)*64 + ko_ + 8*g; \
    _Pragma("unroll") for(int m_=0;m_<4;++m_) dst[m_] = *(const bf16x8*)(sp + (size_t)m_*16*128); \
  } else { \
    const short* sp = (part_==1 ? x1 : y) + ((v0 + r)*256 + w*64 + ko_ + 8*g); \
    _Pragma("unroll") for(int m_=0;m_<4;++m_) dst[m_] = *(const bf16x8*)(sp + (size_t)m_*16*256); \
  } }

__global__ __launch_bounds__(256) void k_gemm_mfma(const short* __restrict__ x0,
                      const short* __restrict__ x1, const short* __restrict__ y,
                      const short* __restrict__ wcb, const float* __restrict__ bias,
                      float* __restrict__ out){
  const int t = threadIdx.x;
  const int w = t>>6;          // wave id = batch b
  const int l = t&63, r = l&15, g = l>>4;
  const size_t v0 = (size_t)blockIdx.x*64;
  f32x4 acc[4][4] = {};
  bf16x8 aC[4], aN[4];
  LOADA(aC, 0);

#pragma unroll
  for(int c=0; c<6; ++c){
    if(c < 5) LOADA(aN, c+1);
    const int part = c>>1, ko = (c&1)*32;
    const int kw = part*64 + ko + 8*g;
#pragma unroll
    for(int n=0;n<4;++n){
      const bf16x8 bfr = *(const bf16x8*)&wcb[(n*16+r)*192 + kw];
#pragma unroll
      for(int m=0;m<4;++m)
        acc[m][n] = __builtin_amdgcn_mfma_f32_16x16x32_bf16(aC[m], bfr, acc[m][n], 0, 0, 0);
    }
    if(c < 5){
#pragma unroll
      for(int m=0;m<4;++m) aC[m] = aN[m];
    }
  }

  __syncthreads();   // all x0c reads (in d_out) done before overwriting with out

  float* ob = out + (size_t)w*Vn*64 + v0*64;
#pragma unroll
  for(int n=0;n<4;++n){
    const float bq = bias[n*16+r];
#pragma unroll
    for(int m=0;m<4;++m){
#pragma unroll
      for(int reg=0;reg<4;++reg){
        const int row = m*16 + g*4 + reg;
        ob[(size_t)row*64 + n*16 + r] = acc[m][n][reg] + bq;
      }
    }
  }
}

// ---------------- launch ----------------

extern "C" void kernel_launch(void* const* d_in, const int* in_sizes, int n_in,
                              void* d_out, int out_size, void* d_ws, size_t ws_size,
                              hipStream_t stream){
  const float* lap_vals = (const float*)d_in[0];
  const float* x        = (const float*)d_in[1];
  const float* weight   = (const float*)d_in[2];
  const float* bias     = (const float*)d_in[3];
  const int*   lap_rows = (const int*)d_in[4];
  const int*   lap_cols = (const int*)d_in[5];
  float* out = (float*)d_out;
  short* x0c = (short*)d_out;   // bf16 x0 staged inside the output buffer

  char* w = (char*)d_ws;
  short* x1b = (short*)w;          w += (size_t)Vn*256*sizeof(short);
  int2* meta = (int2*)w;           w += (size_t)NNZn*8;
  // union region: bmeta+brow (live: k_bucket..k_csr) aliased with yb (live: spmm2..gemm)
  char* uni = w;                   w += (size_t)Vn*256*sizeof(short);   // 100 MB
  int2* bmeta = (int2*)uni;
  int*  brow  = (int*)(uni + (size_t)NNZn*8);
  short* yb   = (short*)uni;
  unsigned* rstart = (unsigned*)w; w += (size_t)Vn*4;
  unsigned* rend   = (unsigned*)w; w += (size_t)Vn*4;
  unsigned* gcount = (unsigned*)w; w += NB*4;
  unsigned* gbase  = (unsigned*)w; w += (NB+1)*4;
  unsigned* gcursor= (unsigned*)w; w += NB*4;
  short* wcb = (short*)w;          w += 12288*sizeof(short);

  hipMemsetAsync(gcount, 0, NB*sizeof(unsigned), stream);
  k_pre<<<25056, 256, 0, stream>>>(lap_rows, gcount, x, x0c, weight, wcb);
  k_scan256<<<1, 256, 0, stream>>>(gcount, gbase, gcursor);
  k_bucket<<<NTIL, 256, 0, stream>>>(lap_rows, lap_cols, lap_vals, gcursor, brow, bmeta);
  k_csr<<<NB, 256, 0, stream>>>(brow, bmeta, gbase, rstart, rend, meta);

  // x1 = L @ x0   (gather from x0c: piece-split rows, 2 x 256B segments)
  k_spmm<128, (size_t)Vn*128><<<Vn/8, 256, 0, stream>>>(x0c, meta, rstart, rend, x1b);
  // y = L @ x1    (gather from x1b: flat rows, contiguous 512B)
  k_spmm<256, 128><<<Vn/8, 256, 0, stream>>>(x1b, meta, rstart, rend, yb);

  k_gemm_mfma<<<Vn/64, 256, 0, stream>>>(x0c, x1b, yb, wcb, bias, out);
}

// Round 14
// 511.671 us; speedup vs baseline: 1.0358x; 1.0358x over previous
//
#include <hip/hip_runtime.h>
#include <hip/hip_bf16.h>

#define Vn   196608
#define NNZn 1769472
#define Bn   4
#define Pn   64
#define Qn   64
#define VPn  (Vn*Pn)
#define NB   256      // buckets
#define RPB  768      // rows per bucket = Vn/NB
#define EPT  4096     // edges per count/bucket tile
#define NTIL 432      // NNZ/EPT

typedef __hip_bfloat16 bf16;
typedef __attribute__((ext_vector_type(8))) short bf16x8;
typedef __attribute__((ext_vector_type(4))) float f32x4;
typedef __attribute__((ext_vector_type(4))) unsigned int u32x4;

__device__ inline short f2bs(float f){
  __hip_bfloat16 h = __float2bfloat16(f);
  return *(short*)&h;
}
__device__ inline float lo16(unsigned u){ return __uint_as_float(u<<16); }
__device__ inline float hi16(unsigned u){ return __uint_as_float(u & 0xffff0000u); }

// ---- fused pre-pass: bucket-count (LDS-aggregated) + cvt + prepw ----------

__global__ __launch_bounds__(256) void k_pre(const int* __restrict__ rows, unsigned* __restrict__ gcount,
                      const float* __restrict__ x, short* __restrict__ x0c,
                      const float* __restrict__ wf, short* __restrict__ wcb){
  __shared__ unsigned hcnt[NB];
  const int bid = blockIdx.x, t = threadIdx.x;
  if(bid % 58 == 0){               // ---- count: LDS hist over 256 buckets
    const int cb = bid/58;
    hcnt[t] = 0u;
    __syncthreads();
    const int base = cb*EPT;
#pragma unroll
    for(int k=0;k<4;++k){
      const int4 r = *(const int4*)(rows + base + k*1024 + t*4);
      atomicAdd(&hcnt[(unsigned)r.x/RPB], 1u);
      atomicAdd(&hcnt[(unsigned)r.y/RPB], 1u);
      atomicAdd(&hcnt[(unsigned)r.z/RPB], 1u);
      atomicAdd(&hcnt[(unsigned)r.w/RPB], 1u);
    }
    __syncthreads();
    atomicAdd(&gcount[t], hcnt[t]);
    return;
  }
  const int f = bid - bid/58 - 1;
  if(f < 24576){                   // ---- cvt: 8 floats -> 8 bf16 per thread
    const int i = f*256 + t;
    const int o = i*8;
    const int v = o>>8, bp = o&255;
    const int hh = bp>>7, w7 = bp&127;
    const int b = (hh<<1) + (w7>>6), p = w7&63;
    const float* xp = x + (size_t)b*VPn + (size_t)v*64 + p;
    const float4 f0 = *(const float4*)xp;
    const float4 f1 = *(const float4*)(xp+4);
    unsigned r0 = ((unsigned)(unsigned short)f2bs(f0.y)<<16) | (unsigned)(unsigned short)f2bs(f0.x);
    unsigned r1 = ((unsigned)(unsigned short)f2bs(f0.w)<<16) | (unsigned)(unsigned short)f2bs(f0.z);
    unsigned r2 = ((unsigned)(unsigned short)f2bs(f1.y)<<16) | (unsigned)(unsigned short)f2bs(f1.x);
    unsigned r3 = ((unsigned)(unsigned short)f2bs(f1.w)<<16) | (unsigned)(unsigned short)f2bs(f1.z);
    u32x4 u; u[0]=r0; u[1]=r1; u[2]=r2; u[3]=r3;
    *(u32x4*)(x0c + ((size_t)hh*Vn + v)*128 + w7) = u;
  } else {                         // ---- prepw: combined weights wcb[q][192]
    const int idx = (f - 24576)*256 + t;         // 12288 total
    const int q = idx/192, rem = idx%192, part = rem>>6, p = rem&63;
    float w;
    if(part==0)      w = wf[(3*p+0)*64+q] - wf[(3*p+2)*64+q];
    else if(part==1) w = wf[(3*p+1)*64+q];
    else             w = 2.0f*wf[(3*p+2)*64+q];
    wcb[idx] = f2bs(w);
  }
}

// ---- scan of 256 bucket counts -> exclusive bases + cursors ----
__global__ void k_scan256(const unsigned* __restrict__ gcount, unsigned* __restrict__ gbase,
                          unsigned* __restrict__ gcursor){
  __shared__ unsigned t[NB];
  const int i = threadIdx.x;
  const unsigned c = gcount[i];
  t[i] = c;
  __syncthreads();
  for(int off=1; off<NB; off<<=1){
    unsigned v = (i>=off) ? t[i-off] : 0u;
    __syncthreads();
    t[i] += v;
    __syncthreads();
  }
  const unsigned excl = t[i] - c;
  gbase[i] = excl;
  gcursor[i] = excl;
  if(i == NB-1) gbase[NB] = t[NB-1];
}

// ---- bucket scatter: edges -> bucket-grouped (brow, bmeta) ----
__global__ __launch_bounds__(256) void k_bucket(const int* __restrict__ rows, const int* __restrict__ cols,
                         const float* __restrict__ vals, unsigned* __restrict__ gcursor,
                         int* __restrict__ brow, int2* __restrict__ bmeta){
  __shared__ unsigned hcnt[NB];
  __shared__ unsigned lcur[NB];
  const int t = threadIdx.x;
  const int base = blockIdx.x*EPT;
  hcnt[t] = 0u;
  __syncthreads();
  int4 r4[4];
#pragma unroll
  for(int k=0;k<4;++k){
    r4[k] = *(const int4*)(rows + base + k*1024 + t*4);
    atomicAdd(&hcnt[(unsigned)r4[k].x/RPB], 1u);
    atomicAdd(&hcnt[(unsigned)r4[k].y/RPB], 1u);
    atomicAdd(&hcnt[(unsigned)r4[k].z/RPB], 1u);
    atomicAdd(&hcnt[(unsigned)r4[k].w/RPB], 1u);
  }
  __syncthreads();
  lcur[t] = atomicAdd(&gcursor[t], hcnt[t]);
  __syncthreads();
#pragma unroll
  for(int k=0;k<4;++k){
    const int4   c4 = *(const int4*)(cols + base + k*1024 + t*4);
    const float4 v4 = *(const float4*)(vals + base + k*1024 + t*4);
    unsigned p;
    p = atomicAdd(&lcur[(unsigned)r4[k].x/RPB],1u); brow[p]=r4[k].x; { int2 m; m.x=c4.x; m.y=__float_as_int(v4.x); bmeta[p]=m; }
    p = atomicAdd(&lcur[(unsigned)r4[k].y/RPB],1u); brow[p]=r4[k].y; { int2 m; m.x=c4.y; m.y=__float_as_int(v4.y); bmeta[p]=m; }
    p = atomicAdd(&lcur[(unsigned)r4[k].z/RPB],1u); brow[p]=r4[k].z; { int2 m; m.x=c4.z; m.y=__float_as_int(v4.z); bmeta[p]=m; }
    p = atomicAdd(&lcur[(unsigned)r4[k].w/RPB],1u); brow[p]=r4[k].w; { int2 m; m.x=c4.w; m.y=__float_as_int(v4.w); bmeta[p]=m; }
  }
}

// ---- per-bucket CSR finalize: one block per bucket, all in LDS ----
__global__ __launch_bounds__(256) void k_csr(const int* __restrict__ brow, const int2* __restrict__ bmeta,
                      const unsigned* __restrict__ gbase,
                      unsigned* __restrict__ rstart, unsigned* __restrict__ rend,
                      int2* __restrict__ meta){
  __shared__ unsigned rcnt[RPB];
  __shared__ unsigned rcur[RPB];
  __shared__ unsigned ssum[256];
  const int t = threadIdx.x, b = blockIdx.x;
  const unsigned base = gbase[b];
  const int nb = (int)(gbase[b+1] - base);
  const int rv0 = b*RPB;
#pragma unroll
  for(int k=0;k<3;++k) rcnt[t*3+k] = 0u;
  __syncthreads();
  for(int e=t; e<nb; e+=256){
    const int r = brow[base+e] - rv0;
    atomicAdd(&rcnt[r], 1u);
  }
  __syncthreads();
  const unsigned c0 = rcnt[t*3], c1 = rcnt[t*3+1], c2 = rcnt[t*3+2];
  const unsigned mysum = c0+c1+c2;
  ssum[t] = mysum;
  __syncthreads();
  for(int off=1; off<256; off<<=1){
    unsigned v = (t>=off) ? ssum[t-off] : 0u;
    __syncthreads();
    ssum[t] += v;
    __syncthreads();
  }
  const unsigned excl = ssum[t] - mysum;
  const unsigned s0 = base + excl, s1 = s0 + c0, s2 = s1 + c1;
  rstart[rv0+t*3+0] = s0;  rend[rv0+t*3+0] = s0 + c0;  rcur[t*3+0] = s0;
  rstart[rv0+t*3+1] = s1;  rend[rv0+t*3+1] = s1 + c1;  rcur[t*3+1] = s1;
  rstart[rv0+t*3+2] = s2;  rend[rv0+t*3+2] = s2 + c2;  rcur[t*3+2] = s2;
  __syncthreads();
  for(int e=t; e<nb; e+=256){
    const int r = brow[base+e] - rv0;
    const unsigned pos = atomicAdd(&rcur[r], 1u);
    meta[pos] = bmeta[base+e];
  }
}

// ---------------- SpMM: TWO rows per wave (R5-proven shape) ---------------

#define SP_STAGE(U,W,I) { int c_=0; float wv_=0.f; \
    if((I) < n){ const int2 m_ = meta[s+(unsigned)(I)]; c_=m_.x; wv_=__int_as_float(m_.y);} \
    W = wv_; U = *(const u32x4*)(src + (size_t)c_*SROW + off); }
#define SP_CONSUME(U,W) { \
    a0=fmaf(W,lo16(U[0]),a0); a1=fmaf(W,hi16(U[0]),a1); \
    a2=fmaf(W,lo16(U[1]),a2); a3=fmaf(W,hi16(U[1]),a3); \
    a4=fmaf(W,lo16(U[2]),a4); a5=fmaf(W,hi16(U[2]),a5); \
    a6=fmaf(W,lo16(U[3]),a6); a7=fmaf(W,hi16(U[3]),a7); }
#define SP_BODY \
  float a0=0,a1=0,a2=0,a3=0,a4=0,a5=0,a6=0,a7=0; \
  if(nmax > 0){ \
    u32x4 u0,u1,u2,u3; float w0,w1,w2,w3; \
    SP_STAGE(u0,w0,0) SP_STAGE(u1,w1,1) SP_STAGE(u2,w2,2) SP_STAGE(u3,w3,3) \
    int rem = nmax - 4; \
    int j = 4; \
    while(rem > 0){ \
      const u32x4 p0=u0, p1=u1, p2=u2, p3=u3; \
      const float q0=w0, q1=w1, q2=w2, q3=w3; \
      SP_STAGE(u0,w0,j) SP_STAGE(u1,w1,j+1) SP_STAGE(u2,w2,j+2) SP_STAGE(u3,w3,j+3) \
      SP_CONSUME(p0,q0) SP_CONSUME(p1,q1) SP_CONSUME(p2,q2) SP_CONSUME(p3,q3) \
      rem -= 4; j += 4; \
    } \
    SP_CONSUME(u0,w0) SP_CONSUME(u1,w1) SP_CONSUME(u2,w2) SP_CONSUME(u3,w3) \
  } \
  unsigned r0 = ((unsigned)(unsigned short)f2bs(a1)<<16) | (unsigned)(unsigned short)f2bs(a0); \
  unsigned r1 = ((unsigned)(unsigned short)f2bs(a3)<<16) | (unsigned)(unsigned short)f2bs(a2); \
  unsigned r2 = ((unsigned)(unsigned short)f2bs(a5)<<16) | (unsigned)(unsigned short)f2bs(a4); \
  unsigned r3 = ((unsigned)(unsigned short)f2bs(a7)<<16) | (unsigned)(unsigned short)f2bs(a6); \
  u32x4 ov; ov[0]=r0; ov[1]=r1; ov[2]=r2; ov[3]=r3;

template<int SROW, size_t PSTR>
__global__ __launch_bounds__(256) void k_spmm(const short* __restrict__ src,
                          const int2* __restrict__ meta,
                          const unsigned* __restrict__ rstart, const unsigned* __restrict__ rend,
                          short* __restrict__ dst){
  const int tid = threadIdx.x;
  const int lane = tid & 63;
  const int half = lane >> 5, sub = lane & 31;
  const int vbase = blockIdx.x*8 + (tid>>6)*2;
  const unsigned sA = rstart[vbase],   sB = rstart[vbase+1];
  const int nA = (int)(rend[vbase]-sA), nB = (int)(rend[vbase+1]-sB);
  const int nmax = (nA > nB) ? nA : nB;
  const unsigned s = half ? sB : sA;
  const int n = half ? nB : nA;
  const size_t off = (size_t)(sub>>4)*PSTR + (size_t)((sub&15)*8);
  SP_BODY
  *(u32x4*)(dst + (size_t)(vbase+half)*256 + sub*8) = ov;
}

// ---------------- MFMA GEMM epilogue (R11-proven: LDS-staged weights) ------
// out[b,v,q] = bias[q] + sum_k3 A[v-row,k3] * Wc[k3,q]
// A parts: [0,64): x0 (bf16, from x0c in d_out); [64,128): x1; [128,192): y.
// mfma_f32_16x16x32_bf16: A row=l&15, k=8*(l>>4)+i; C/D col=l&15, row=4*(l>>4)+reg.

#define WTP 200   // LDS pitch in bf16 elems: bank stride 4 -> conflict-free

#define LOADA(dst, cc) { \
  const int part_ = (cc)>>1, ko_ = ((cc)&1)*32; \
  if(part_==0){ \
    const short* sp = x0 + ((size_t)(w>>1)*Vn + v0 + r)*128 + (w&1)*64 + ko_ + 8*g; \
    _Pragma("unroll") for(int m_=0;m_<4;++m_) dst[m_] = *(const bf16x8*)(sp + (size_t)m_*16*128); \
  } else { \
    const short* sp = (part_==1 ? x1 : y) + ((v0 + r)*256 + w*64 + ko_ + 8*g); \
    _Pragma("unroll") for(int m_=0;m_<4;++m_) dst[m_] = *(const bf16x8*)(sp + (size_t)m_*16*256); \
  } }

__global__ __launch_bounds__(256) void k_gemm_mfma(const short* __restrict__ x0,
                      const short* __restrict__ x1, const short* __restrict__ y,
                      const short* __restrict__ wcb, const float* __restrict__ bias,
                      float* __restrict__ out){
  __shared__ short WT[64*WTP];    // 25600 B, [q][k3] padded
  const int t = threadIdx.x;
  for(int idx=t; idx<1536; idx+=256){
    const int row = idx/24, ch = idx%24;
    *(uint4*)&WT[row*WTP + ch*8] = ((const uint4*)wcb)[row*24 + ch];
  }
  const int w = t>>6;          // wave id = batch b
  const int l = t&63, r = l&15, g = l>>4;
  const size_t v0 = (size_t)blockIdx.x*64;
  f32x4 acc[4][4] = {};
  bf16x8 aC[4], aN[4];
  LOADA(aC, 0);
  __syncthreads();

#pragma unroll
  for(int c=0; c<6; ++c){
    if(c < 5) LOADA(aN, c+1);
    const int part = c>>1, ko = (c&1)*32;
    const int kw = part*64 + ko + 8*g;
#pragma unroll
    for(int n=0;n<4;++n){
      const bf16x8 bfr = *(const bf16x8*)&WT[(n*16+r)*WTP + kw];
#pragma unroll
      for(int m=0;m<4;++m)
        acc[m][n] = __builtin_amdgcn_mfma_f32_16x16x32_bf16(aC[m], bfr, acc[m][n], 0, 0, 0);
    }
    if(c < 5){
#pragma unroll
      for(int m=0;m<4;++m) aC[m] = aN[m];
    }
  }

  __syncthreads();   // all x0c reads (in d_out) done before overwriting with out

  float* ob = out + (size_t)w*Vn*64 + v0*64;
#pragma unroll
  for(int n=0;n<4;++n){
    const float bq = bias[n*16+r];
#pragma unroll
    for(int m=0;m<4;++m){
#pragma unroll
      for(int reg=0;reg<4;++reg){
        const int row = m*16 + g*4 + reg;
        ob[(size_t)row*64 + n*16 + r] = acc[m][n][reg] + bq;
      }
    }
  }
}

// ---------------- launch ----------------

extern "C" void kernel_launch(void* const* d_in, const int* in_sizes, int n_in,
                              void* d_out, int out_size, void* d_ws, size_t ws_size,
                              hipStream_t stream){
  const float* lap_vals = (const float*)d_in[0];
  const float* x        = (const float*)d_in[1];
  const float* weight   = (const float*)d_in[2];
  const float* bias     = (const float*)d_in[3];
  const int*   lap_rows = (const int*)d_in[4];
  const int*   lap_cols = (const int*)d_in[5];
  float* out = (float*)d_out;
  short* x0c = (short*)d_out;   // bf16 x0 staged inside the output buffer

  char* w = (char*)d_ws;
  short* x1b = (short*)w;          w += (size_t)Vn*256*sizeof(short);
  int2* meta = (int2*)w;           w += (size_t)NNZn*8;
  // union region: bmeta+brow (live: k_bucket..k_csr) aliased with yb (live: spmm2..gemm)
  char* uni = w;                   w += (size_t)Vn*256*sizeof(short);   // 100 MB
  int2* bmeta = (int2*)uni;
  int*  brow  = (int*)(uni + (size_t)NNZn*8);
  short* yb   = (short*)uni;
  unsigned* rstart = (unsigned*)w; w += (size_t)Vn*4;
  unsigned* rend   = (unsigned*)w; w += (size_t)Vn*4;
  unsigned* gcount = (unsigned*)w; w += NB*4;
  unsigned* gbase  = (unsigned*)w; w += (NB+1)*4;
  unsigned* gcursor= (unsigned*)w; w += NB*4;
  short* wcb = (short*)w;          w += 12288*sizeof(short);

  hipMemsetAsync(gcount, 0, NB*sizeof(unsigned), stream);
  k_pre<<<25056, 256, 0, stream>>>(lap_rows, gcount, x, x0c, weight, wcb);
  k_scan256<<<1, 256, 0, stream>>>(gcount, gbase, gcursor);
  k_bucket<<<NTIL, 256, 0, stream>>>(lap_rows, lap_cols, lap_vals, gcursor, brow, bmeta);
  k_csr<<<NB, 256, 0, stream>>>(brow, bmeta, gbase, rstart, rend, meta);

  // x1 = L @ x0   (gather from x0c: piece-split rows, 2 x 256B segments)
  k_spmm<128, (size_t)Vn*128><<<Vn/8, 256, 0, stream>>>(x0c, meta, rstart, rend, x1b);
  // y = L @ x1    (gather from x1b: flat rows, contiguous 512B)
  k_spmm<256, 128><<<Vn/8, 256, 0, stream>>>(x1b, meta, rstart, rend, yb);

  k_gemm_mfma<<<Vn/64, 256, 0, stream>>>(x0c, x1b, yb, wcb, bias, out);
}